// Round 7
// baseline (170.285 us; speedup 1.0000x reference)
//
#include <hip/hip_runtime.h>
#include <math.h>

#define BATCH 4
#define CH    256
#define CQK   32
#define NPIX  4096   // 64*64
#define NT    32     // KV steps of 128 keys each
#define LOG2E 1.4426950408889634f

typedef __attribute__((ext_vector_type(8))) short short8;   // 8 bf16 (4 VGPRs)
typedef __attribute__((ext_vector_type(4))) float f32x4;

static __device__ __forceinline__ unsigned short f2bf(float f) {
    unsigned u = __builtin_bit_cast(unsigned, f);
    u = (u + 0x7fffu + ((u >> 16) & 1u)) >> 16;   // RNE
    return (unsigned short)u;
}
static __device__ __forceinline__ float bf2f(unsigned short s) {
    unsigned u = ((unsigned)s) << 16;
    return __builtin_bit_cast(float, u);
}
static __device__ __forceinline__ float exp2_fast(float x) {
    float r; asm("v_exp_f32 %0, %1" : "=v"(r) : "v"(x)); return r;
}
static __device__ __forceinline__ unsigned cvt_pk_bf16(float lo, float hi) {
    unsigned r; asm("v_cvt_pk_bf16_f32 %0, %1, %2" : "=v"(r) : "v"(lo), "v"(hi)); return r;
}

// ---------------------------------------------------------------------------
// Kernel 0: W -> bf16 hi/lo. Q rows pre-scaled by log2(e) (base-2 softmax).
// ---------------------------------------------------------------------------
__global__ __launch_bounds__(256) void wcvt_kernel(
    const float* __restrict__ wq, const float* __restrict__ wk,
    const float* __restrict__ wv,
    unsigned short* __restrict__ Wh, unsigned short* __restrict__ Wl)
{
    int idx = blockIdx.x * 256 + threadIdx.x;   // 0..81919
    int r = idx >> 8, c = idx & 255;
    float f;
    if (r < 32)       f = wq[r * 256 + c] * LOG2E;
    else if (r < 64)  f = wk[(r - 32) * 256 + c];
    else              f = wv[(r - 64) * 256 + c];
    unsigned short h = f2bf(f);
    Wh[idx] = h;
    Wl[idx] = f2bf(f - bf2f(h));
}

// ---------------------------------------------------------------------------
// Kernel 1: q/k/v projections as compensated-bf16 MFMA GEMM.
//   Outputs: Qh/Ql (hi/lo), Kh (hi only) [b][n][32]; Vb [b][c][n].
// ---------------------------------------------------------------------------
__global__ __launch_bounds__(256) void qkv_kernel(
    const float* __restrict__ x,
    const float* __restrict__ bq, const float* __restrict__ bk,
    const float* __restrict__ bv,
    const unsigned short* __restrict__ Wh, const unsigned short* __restrict__ Wl,
    unsigned short* __restrict__ Qh, unsigned short* __restrict__ Ql,
    unsigned short* __restrict__ Kh, unsigned short* __restrict__ Vb)
{
    __shared__ __align__(16) unsigned short Xh[32 * 256];  // swizzled [n][c]
    __shared__ __align__(16) unsigned short Xl[32 * 256];

    const int b  = blockIdx.y;
    const int n0 = blockIdx.x * 32;
    const int t  = threadIdx.x;

    #pragma unroll
    for (int rep = 0; rep < 8; ++rep) {
        int idx = rep * 256 + t;       // float4 units
        int c = idx >> 3, n4 = idx & 7;
        float4 xv = *(const float4*)&x[((size_t)b * CH + c) * NPIX + n0 + n4 * 4];
        #pragma unroll
        for (int u = 0; u < 4; ++u) {
            int n = n4 * 4 + u;
            float f = (&xv.x)[u];
            unsigned short h = f2bf(f);
            unsigned short l = f2bf(f - bf2f(h));
            int off = n * 512 + (((c >> 3) * 16) ^ ((n & 7) << 4)) + (c & 7) * 2;
            *(unsigned short*)((char*)Xh + off) = h;
            *(unsigned short*)((char*)Xl + off) = l;
        }
    }
    __syncthreads();

    const int w = t >> 6, l = t & 63, g = l >> 4, m = l & 15;

    for (int dt = 0; dt < 5; ++dt) {
        const int d0 = w * 80 + dt * 16;

        short8 wh[8], wl[8];
        #pragma unroll
        for (int ks = 0; ks < 8; ++ks) {
            size_t off = (size_t)(d0 + m) * 256 + ks * 32 + g * 8;
            wh[ks] = __builtin_bit_cast(short8, *(const uint4*)&Wh[off]);
            wl[ks] = __builtin_bit_cast(short8, *(const uint4*)&Wl[off]);
        }

        f32x4 acc[2];
        acc[0] = (f32x4){0.f, 0.f, 0.f, 0.f};
        acc[1] = (f32x4){0.f, 0.f, 0.f, 0.f};
        #pragma unroll
        for (int nt = 0; nt < 2; ++nt) {
            const int n = nt * 16 + m;
            #pragma unroll
            for (int ks = 0; ks < 8; ++ks) {
                int off = n * 512 + (((ks * 4 + g) * 16) ^ ((n & 7) << 4));
                short8 xh = __builtin_bit_cast(short8, *(const uint4*)((char*)Xh + off));
                short8 xl = __builtin_bit_cast(short8, *(const uint4*)((char*)Xl + off));
                acc[nt] = __builtin_amdgcn_mfma_f32_16x16x32_bf16(wh[ks], xh, acc[nt], 0, 0, 0);
                acc[nt] = __builtin_amdgcn_mfma_f32_16x16x32_bf16(wh[ks], xl, acc[nt], 0, 0, 0);
                acc[nt] = __builtin_amdgcn_mfma_f32_16x16x32_bf16(wl[ks], xh, acc[nt], 0, 0, 0);
            }
        }

        int kind;                      // 0=Q, 1=K, 2=V
        float4 bias;
        if (d0 < 32)      { kind = 0; bias = *(const float4*)&bq[d0 + g * 4];
                            bias.x *= LOG2E; bias.y *= LOG2E; bias.z *= LOG2E; bias.w *= LOG2E; }
        else if (d0 < 64) { kind = 1; bias = *(const float4*)&bk[d0 - 32 + g * 4]; }
        else              { kind = 2; bias = *(const float4*)&bv[d0 - 64 + g * 4]; }

        #pragma unroll
        for (int nt = 0; nt < 2; ++nt) {
            const int n = n0 + nt * 16 + m;
            if (kind == 2) {
                const int c0 = d0 - 64;
                #pragma unroll
                for (int r = 0; r < 4; ++r) {
                    float val = acc[nt][r] + (&bias.x)[r];
                    Vb[((size_t)b * CH + c0 + g * 4 + r) * NPIX + n] = f2bf(val);
                }
            } else {
                float val[4];
                unsigned short hs[4];
                #pragma unroll
                for (int r = 0; r < 4; ++r) {
                    val[r] = acc[nt][r] + (&bias.x)[r];
                    hs[r] = f2bf(val[r]);
                }
                const int dcol = (d0 & 31) + g * 4;
                const size_t base = ((size_t)b * NPIX + n) * CQK + dcol;
                uint2 uh;
                uh.x = (unsigned)hs[0] | ((unsigned)hs[1] << 16);
                uh.y = (unsigned)hs[2] | ((unsigned)hs[3] << 16);
                if (kind == 0) {
                    unsigned short ls[4];
                    #pragma unroll
                    for (int r = 0; r < 4; ++r) ls[r] = f2bf(val[r] - bf2f(hs[r]));
                    uint2 ul;
                    ul.x = (unsigned)ls[0] | ((unsigned)ls[1] << 16);
                    ul.y = (unsigned)ls[2] | ((unsigned)ls[3] << 16);
                    *(uint2*)&Qh[base] = uh;
                    *(uint2*)&Ql[base] = ul;
                } else {
                    *(uint2*)&Kh[base] = uh;
                }
            }
        }
    }
}

// ---------------------------------------------------------------------------
// Kernel 2: flash attention, i-tile 32, grid 512 (2 blocks/CU).
//   4 waves: 0-1 producers (16 i-rows each: QK^T from global-K regs,
//   base-2 softmax, P pack), 2-3 consumers (128 channels each: PV).
//   No K LDS staging: K frags register-resident, reloaded from L2 per step
//   (loads issued right after MFMA consume -> latency under softmax).
//   LDS: only P double-buffer (16KB) + sFac/sL. One barrier per step.
// ---------------------------------------------------------------------------

#define PROD_STEP(JT) do {                                                     \
    const int _idx = (JT) & 1;                                                 \
    f32x4 sv[8];                                                               \
    _Pragma("unroll")                                                          \
    for (int jf = 0; jf < 8; ++jf) {                                           \
        f32x4 s = (f32x4){0.f, 0.f, 0.f, 0.f};                                 \
        s = __builtin_amdgcn_mfma_f32_16x16x32_bf16(kA[jf], qh, s, 0, 0, 0);   \
        s = __builtin_amdgcn_mfma_f32_16x16x32_bf16(kA[jf], ql, s, 0, 0, 0);   \
        sv[jf] = s;                                                            \
    }                                                                          \
    if ((JT) + 1 < NT) {                                                       \
        _Pragma("unroll")                                                      \
        for (int jf = 0; jf < 8; ++jf)                                         \
            kA[jf] = __builtin_bit_cast(short8, *(const uint4*)&Kh[            \
                kfb + (size_t)(((JT) + 1) * 128 + jf * 16) * CQK]);            \
    }                                                                          \
    float s32[32];                                                             \
    _Pragma("unroll")                                                          \
    for (int jf = 0; jf < 8; ++jf)                                             \
        _Pragma("unroll")                                                      \
        for (int r = 0; r < 4; ++r) s32[jf * 4 + r] = sv[jf][r];               \
    float mx[16];                                                              \
    _Pragma("unroll")                                                          \
    for (int k = 0; k < 16; ++k) mx[k] = fmaxf(s32[k], s32[k + 16]);           \
    _Pragma("unroll")                                                          \
    for (int k = 0; k < 8; ++k) mx[k] = fmaxf(mx[k], mx[k + 8]);               \
    _Pragma("unroll")                                                          \
    for (int k = 0; k < 4; ++k) mx[k] = fmaxf(mx[k], mx[k + 4]);               \
    float tmax = fmaxf(fmaxf(mx[0], mx[2]), fmaxf(mx[1], mx[3]));              \
    float fac = 1.0f;                                                          \
    if (!__all(tmax <= m_run + 11.5f)) {                                       \
        float tc = fmaxf(tmax, __shfl_xor(tmax, 16));                          \
        tc = fmaxf(tc, __shfl_xor(tc, 32));                                    \
        float mt = fmaxf(m_run, tc);                                           \
        fac = exp2_fast(m_run - mt);                                           \
        m_run = mt;                                                            \
    }                                                                          \
    float p[32];                                                               \
    _Pragma("unroll")                                                          \
    for (int k = 0; k < 32; ++k) p[k] = exp2_fast(s32[k] - m_run);             \
    float sm[16];                                                              \
    _Pragma("unroll")                                                          \
    for (int k = 0; k < 16; ++k) sm[k] = p[k] + p[k + 16];                     \
    _Pragma("unroll")                                                          \
    for (int k = 0; k < 8; ++k) sm[k] = sm[k] + sm[k + 8];                     \
    _Pragma("unroll")                                                          \
    for (int k = 0; k < 4; ++k) sm[k] = sm[k] + sm[k + 4];                     \
    float tsum = (sm[0] + sm[2]) + (sm[1] + sm[3]);                            \
    tsum += __shfl_xor(tsum, 16);                                              \
    tsum += __shfl_xor(tsum, 32);                                              \
    l_run = l_run * fac + tsum;                                                \
    if (g == 0) sFac[_idx][irow] = fac;                                        \
    char* pb = (char*)Pbuf[_idx];                                              \
    _Pragma("unroll")                                                          \
    for (int jf = 0; jf < 8; ++jf) {                                           \
        uint2 u;                                                               \
        u.x = cvt_pk_bf16(p[jf * 4 + 0], p[jf * 4 + 1]);                       \
        u.y = cvt_pk_bf16(p[jf * 4 + 2], p[jf * 4 + 3]);                       \
        *(uint2*)(pb + irow * 256 + ((jf * 32 + g * 8) ^ (m << 4))) = u;       \
    }                                                                          \
} while (0)

#define CONS_STEP(JT) do {                                                     \
    const int _jb   = ((JT) - 1) * 128;                                        \
    const int _pidx = ((JT) & 1) ^ 1;                                          \
    const char* pb = (const char*)Pbuf[_pidx];                                 \
    uint4 v0[16];                                                              \
    _Pragma("unroll")                                                          \
    for (int cf = 0; cf < 8; ++cf) {                                           \
        v0[cf * 2]     = *(const uint4*)&vbase[(size_t)cf * 16 * NPIX + _jb + g * 8];      \
        v0[cf * 2 + 1] = *(const uint4*)&vbase[(size_t)cf * 16 * NPIX + _jb + 32 + g * 8]; \
    }                                                                          \
    short8 pf0[2][2];                                                          \
    _Pragma("unroll")                                                          \
    for (int f = 0; f < 2; ++f)                                                \
        _Pragma("unroll")                                                      \
        for (int kk = 0; kk < 2; ++kk)                                         \
            pf0[f][kk] = __builtin_bit_cast(short8, *(const uint4*)(pb +       \
                (f * 16 + m) * 256 + ((kk * 64 + g * 16) ^ (m << 4))));        \
    float ff0 = sFac[_pidx][m], ff1 = sFac[_pidx][16 + m];                     \
    if (!__all(ff0 == 1.f && ff1 == 1.f)) {                                    \
        _Pragma("unroll")                                                      \
        for (int cf = 0; cf < 8; ++cf) { acc[cf][0] *= ff0; acc[cf][1] *= ff1; } \
    }                                                                          \
    __builtin_amdgcn_s_setprio(1);                                             \
    _Pragma("unroll")                                                          \
    for (int cf = 0; cf < 8; ++cf) {                                           \
        short8 va = __builtin_bit_cast(short8, v0[cf * 2]);                    \
        short8 vb2 = __builtin_bit_cast(short8, v0[cf * 2 + 1]);               \
        acc[cf][0] = __builtin_amdgcn_mfma_f32_16x16x32_bf16(va,  pf0[0][0], acc[cf][0], 0, 0, 0); \
        acc[cf][0] = __builtin_amdgcn_mfma_f32_16x16x32_bf16(vb2, pf0[0][1], acc[cf][0], 0, 0, 0); \
        acc[cf][1] = __builtin_amdgcn_mfma_f32_16x16x32_bf16(va,  pf0[1][0], acc[cf][1], 0, 0, 0); \
        acc[cf][1] = __builtin_amdgcn_mfma_f32_16x16x32_bf16(vb2, pf0[1][1], acc[cf][1], 0, 0, 0); \
    }                                                                          \
    __builtin_amdgcn_s_setprio(0);                                             \
    uint4 v1[16];                                                              \
    _Pragma("unroll")                                                          \
    for (int cf = 0; cf < 8; ++cf) {                                           \
        v1[cf * 2]     = *(const uint4*)&vbase[(size_t)cf * 16 * NPIX + _jb + 64 + g * 8]; \
        v1[cf * 2 + 1] = *(const uint4*)&vbase[(size_t)cf * 16 * NPIX + _jb + 96 + g * 8]; \
    }                                                                          \
    short8 pf1[2][2];                                                          \
    _Pragma("unroll")                                                          \
    for (int f = 0; f < 2; ++f)                                                \
        _Pragma("unroll")                                                      \
        for (int kk = 0; kk < 2; ++kk)                                         \
            pf1[f][kk] = __builtin_bit_cast(short8, *(const uint4*)(pb +       \
                (f * 16 + m) * 256 + (((kk + 2) * 64 + g * 16) ^ (m << 4))));  \
    __builtin_amdgcn_s_setprio(1);                                             \
    _Pragma("unroll")                                                          \
    for (int cf = 0; cf < 8; ++cf) {                                           \
        short8 va = __builtin_bit_cast(short8, v1[cf * 2]);                    \
        short8 vb2 = __builtin_bit_cast(short8, v1[cf * 2 + 1]);               \
        acc[cf][0] = __builtin_amdgcn_mfma_f32_16x16x32_bf16(va,  pf1[0][0], acc[cf][0], 0, 0, 0); \
        acc[cf][0] = __builtin_amdgcn_mfma_f32_16x16x32_bf16(vb2, pf1[0][1], acc[cf][0], 0, 0, 0); \
        acc[cf][1] = __builtin_amdgcn_mfma_f32_16x16x32_bf16(va,  pf1[1][0], acc[cf][1], 0, 0, 0); \
        acc[cf][1] = __builtin_amdgcn_mfma_f32_16x16x32_bf16(vb2, pf1[1][1], acc[cf][1], 0, 0, 0); \
    }                                                                          \
    __builtin_amdgcn_s_setprio(0);                                             \
} while (0)

__global__ __launch_bounds__(256, 2) void attn_kernel(
    const unsigned short* __restrict__ Qh, const unsigned short* __restrict__ Ql,
    const unsigned short* __restrict__ Kh, const unsigned short* __restrict__ Vb,
    const float* __restrict__ x, const float* __restrict__ gamma,
    float* __restrict__ out)
{
    __shared__ __align__(16) uint4 Pbuf[2][512];   // P: 32 rows x 256B, swizzled
    __shared__ float sFac[2][32];
    __shared__ float sL[32];

    // XCD swizzle: XCD pair per batch; (bid&1) = i-range half per XCD
    const int bid = blockIdx.x;
    const int b   = (bid & 7) >> 1;
    const int it  = (bid >> 3) + ((bid & 1) << 6);
    const int i0  = it * 32;

    const int t   = threadIdx.x;
    const int wv4 = t >> 6;
    const bool isProd = (wv4 < 2);
    const int w   = wv4 & 1;
    const int l   = t & 63, g = l >> 4, m = l & 15;
    const int irow = w * 16 + m;

    // ---- producer state ----
    short8 qh = {}, ql = {}, kA[8];
    #pragma unroll
    for (int jf = 0; jf < 8; ++jf) kA[jf] = short8{};
    float m_run = -1e30f, l_run = 0.f;
    size_t kfb = 0;
    if (isProd) {
        const int iq = i0 + irow;
        qh = __builtin_bit_cast(short8, *(const uint4*)&Qh[((size_t)b * NPIX + iq) * CQK + g * 8]);
        ql = __builtin_bit_cast(short8, *(const uint4*)&Ql[((size_t)b * NPIX + iq) * CQK + g * 8]);
        kfb = ((size_t)b * NPIX + m) * CQK + g * 8;
        #pragma unroll
        for (int jf = 0; jf < 8; ++jf)
            kA[jf] = __builtin_bit_cast(short8, *(const uint4*)&Kh[kfb + (size_t)(jf * 16) * CQK]);
    }

    // ---- consumer state ----
    f32x4 acc[8][2];
    #pragma unroll
    for (int cf = 0; cf < 8; ++cf) {
        acc[cf][0] = (f32x4){0.f, 0.f, 0.f, 0.f};
        acc[cf][1] = (f32x4){0.f, 0.f, 0.f, 0.f};
    }
    const unsigned short* vbase = Vb;
    if (!isProd)
        vbase = Vb + ((size_t)b * CH + w * 128 + m) * NPIX;

    for (int jt = 0; jt < NT; ++jt) {
        if (isProd)          PROD_STEP(jt);
        else if (jt >= 1)    CONS_STEP(jt);
        __syncthreads();
    }

    // ---- tail: publish denominators, final PV, epilogue ----
    if (isProd) {
        if (g == 0) sL[irow] = l_run;
    }
    __syncthreads();
    if (!isProd) {
        CONS_STEP(NT);
        const float gm = gamma[0];
        #pragma unroll
        for (int f = 0; f < 2; ++f) {
            float linv = 1.0f / sL[f * 16 + m];
            #pragma unroll
            for (int cf = 0; cf < 8; ++cf) {
                #pragma unroll
                for (int r = 0; r < 4; ++r) {
                    int c = w * 128 + cf * 16 + g * 4 + r;
                    size_t o = ((size_t)b * CH + c) * NPIX + i0 + f * 16 + m;
                    out[o] = gm * acc[cf][f][r] * linv + x[o];
                }
            }
        }
    }
}

extern "C" void kernel_launch(void* const* d_in, const int* in_sizes, int n_in,
                              void* d_out, int out_size, void* d_ws, size_t ws_size,
                              hipStream_t stream) {
    const float* x     = (const float*)d_in[0];
    const float* wq    = (const float*)d_in[1];
    const float* bq    = (const float*)d_in[2];
    const float* wk    = (const float*)d_in[3];
    const float* bk    = (const float*)d_in[4];
    const float* wv    = (const float*)d_in[5];
    const float* bv    = (const float*)d_in[6];
    const float* gamma = (const float*)d_in[7];
    float* out = (float*)d_out;

    // ws layout (bf16): Qh|Ql|Kh (1MB each) | Vb (8MB) | Wh|Wl (160KB each)
    unsigned short* base = (unsigned short*)d_ws;
    const size_t qk_sz = (size_t)BATCH * NPIX * CQK;   // 524288
    unsigned short* Qh = base;
    unsigned short* Ql = Qh + qk_sz;
    unsigned short* Kh = Ql + qk_sz;
    unsigned short* Vb = Kh + qk_sz;
    unsigned short* Wh = Vb + (size_t)BATCH * CH * NPIX;
    unsigned short* Wl = Wh + 320 * 256;

    wcvt_kernel<<<320, 256, 0, stream>>>(wq, wk, wv, Wh, Wl);
    qkv_kernel<<<dim3(128, 4), 256, 0, stream>>>(x, bq, bk, bv, Wh, Wl,
                                                 Qh, Ql, Kh, Vb);
    attn_kernel<<<512, 256, 0, stream>>>(Qh, Ql, Kh, Vb, x, gamma, out);
}

// Round 8
// 123.012 us; speedup vs baseline: 1.3843x; 1.3843x over previous
//
#include <hip/hip_runtime.h>
#include <math.h>

#define BATCH 4
#define CH    256
#define CQK   32
#define NPIX  4096   // 64*64
#define NT    16     // KV steps of 256 keys each
#define LOG2E 1.4426950408889634f

typedef __attribute__((ext_vector_type(8))) short short8;   // 8 bf16 (4 VGPRs)
typedef __attribute__((ext_vector_type(4))) float f32x4;

static __device__ __forceinline__ unsigned short f2bf(float f) {
    unsigned u = __builtin_bit_cast(unsigned, f);
    u = (u + 0x7fffu + ((u >> 16) & 1u)) >> 16;   // RNE
    return (unsigned short)u;
}
static __device__ __forceinline__ float bf2f(unsigned short s) {
    unsigned u = ((unsigned)s) << 16;
    return __builtin_bit_cast(float, u);
}
static __device__ __forceinline__ float exp2_fast(float x) {
    float r; asm("v_exp_f32 %0, %1" : "=v"(r) : "v"(x)); return r;
}
static __device__ __forceinline__ unsigned cvt_pk_bf16(float lo, float hi) {
    unsigned r; asm("v_cvt_pk_bf16_f32 %0, %1, %2" : "=v"(r) : "v"(lo), "v"(hi)); return r;
}

// ---------------------------------------------------------------------------
// Kernel 0: W -> bf16 hi/lo. Q rows pre-scaled by log2(e) (base-2 softmax).
// ---------------------------------------------------------------------------
__global__ __launch_bounds__(256) void wcvt_kernel(
    const float* __restrict__ wq, const float* __restrict__ wk,
    const float* __restrict__ wv,
    unsigned short* __restrict__ Wh, unsigned short* __restrict__ Wl)
{
    int idx = blockIdx.x * 256 + threadIdx.x;   // 0..81919
    int r = idx >> 8, c = idx & 255;
    float f;
    if (r < 32)       f = wq[r * 256 + c] * LOG2E;
    else if (r < 64)  f = wk[(r - 32) * 256 + c];
    else              f = wv[(r - 64) * 256 + c];
    unsigned short h = f2bf(f);
    Wh[idx] = h;
    Wl[idx] = f2bf(f - bf2f(h));
}

// ---------------------------------------------------------------------------
// Kernel 1: q/k/v projections as compensated-bf16 MFMA GEMM.
//   Outputs: Qh/Ql (hi/lo), Kh (hi only) [b][n][32]; Vb [b][c][n].
// ---------------------------------------------------------------------------
__global__ __launch_bounds__(256) void qkv_kernel(
    const float* __restrict__ x,
    const float* __restrict__ bq, const float* __restrict__ bk,
    const float* __restrict__ bv,
    const unsigned short* __restrict__ Wh, const unsigned short* __restrict__ Wl,
    unsigned short* __restrict__ Qh, unsigned short* __restrict__ Ql,
    unsigned short* __restrict__ Kh, unsigned short* __restrict__ Vb)
{
    __shared__ __align__(16) unsigned short Xh[32 * 256];  // swizzled [n][c]
    __shared__ __align__(16) unsigned short Xl[32 * 256];

    const int b  = blockIdx.y;
    const int n0 = blockIdx.x * 32;
    const int t  = threadIdx.x;

    #pragma unroll
    for (int rep = 0; rep < 8; ++rep) {
        int idx = rep * 256 + t;       // float4 units
        int c = idx >> 3, n4 = idx & 7;
        float4 xv = *(const float4*)&x[((size_t)b * CH + c) * NPIX + n0 + n4 * 4];
        #pragma unroll
        for (int u = 0; u < 4; ++u) {
            int n = n4 * 4 + u;
            float f = (&xv.x)[u];
            unsigned short h = f2bf(f);
            unsigned short l = f2bf(f - bf2f(h));
            int off = n * 512 + (((c >> 3) * 16) ^ ((n & 7) << 4)) + (c & 7) * 2;
            *(unsigned short*)((char*)Xh + off) = h;
            *(unsigned short*)((char*)Xl + off) = l;
        }
    }
    __syncthreads();

    const int w = t >> 6, l = t & 63, g = l >> 4, m = l & 15;

    for (int dt = 0; dt < 5; ++dt) {
        const int d0 = w * 80 + dt * 16;

        short8 wh[8], wl[8];
        #pragma unroll
        for (int ks = 0; ks < 8; ++ks) {
            size_t off = (size_t)(d0 + m) * 256 + ks * 32 + g * 8;
            wh[ks] = __builtin_bit_cast(short8, *(const uint4*)&Wh[off]);
            wl[ks] = __builtin_bit_cast(short8, *(const uint4*)&Wl[off]);
        }

        f32x4 acc[2];
        acc[0] = (f32x4){0.f, 0.f, 0.f, 0.f};
        acc[1] = (f32x4){0.f, 0.f, 0.f, 0.f};
        #pragma unroll
        for (int nt = 0; nt < 2; ++nt) {
            const int n = nt * 16 + m;
            #pragma unroll
            for (int ks = 0; ks < 8; ++ks) {
                int off = n * 512 + (((ks * 4 + g) * 16) ^ ((n & 7) << 4));
                short8 xh = __builtin_bit_cast(short8, *(const uint4*)((char*)Xh + off));
                short8 xl = __builtin_bit_cast(short8, *(const uint4*)((char*)Xl + off));
                acc[nt] = __builtin_amdgcn_mfma_f32_16x16x32_bf16(wh[ks], xh, acc[nt], 0, 0, 0);
                acc[nt] = __builtin_amdgcn_mfma_f32_16x16x32_bf16(wh[ks], xl, acc[nt], 0, 0, 0);
                acc[nt] = __builtin_amdgcn_mfma_f32_16x16x32_bf16(wl[ks], xh, acc[nt], 0, 0, 0);
            }
        }

        int kind;                      // 0=Q, 1=K, 2=V
        float4 bias;
        if (d0 < 32)      { kind = 0; bias = *(const float4*)&bq[d0 + g * 4];
                            bias.x *= LOG2E; bias.y *= LOG2E; bias.z *= LOG2E; bias.w *= LOG2E; }
        else if (d0 < 64) { kind = 1; bias = *(const float4*)&bk[d0 - 32 + g * 4]; }
        else              { kind = 2; bias = *(const float4*)&bv[d0 - 64 + g * 4]; }

        #pragma unroll
        for (int nt = 0; nt < 2; ++nt) {
            const int n = n0 + nt * 16 + m;
            if (kind == 2) {
                const int c0 = d0 - 64;
                #pragma unroll
                for (int r = 0; r < 4; ++r) {
                    float val = acc[nt][r] + (&bias.x)[r];
                    Vb[((size_t)b * CH + c0 + g * 4 + r) * NPIX + n] = f2bf(val);
                }
            } else {
                float val[4];
                unsigned short hs[4];
                #pragma unroll
                for (int r = 0; r < 4; ++r) {
                    val[r] = acc[nt][r] + (&bias.x)[r];
                    hs[r] = f2bf(val[r]);
                }
                const int dcol = (d0 & 31) + g * 4;
                const size_t base = ((size_t)b * NPIX + n) * CQK + dcol;
                uint2 uh;
                uh.x = (unsigned)hs[0] | ((unsigned)hs[1] << 16);
                uh.y = (unsigned)hs[2] | ((unsigned)hs[3] << 16);
                if (kind == 0) {
                    unsigned short ls[4];
                    #pragma unroll
                    for (int r = 0; r < 4; ++r) ls[r] = f2bf(val[r] - bf2f(hs[r]));
                    uint2 ul;
                    ul.x = (unsigned)ls[0] | ((unsigned)ls[1] << 16);
                    ul.y = (unsigned)ls[2] | ((unsigned)ls[3] << 16);
                    *(uint2*)&Qh[base] = uh;
                    *(uint2*)&Ql[base] = ul;
                } else {
                    *(uint2*)&Kh[base] = uh;
                }
            }
        }
    }
}

// ---------------------------------------------------------------------------
// Kernel 2: flash attention, producer/consumer waves, KVBLK = 256, NT = 16.
//   512 threads: waves 0-3 producers (QK^T 16 tiles x 2 compensated MFMA +
//   base-2 softmax with __all-gated defer-max + P pack), waves 4-7 consumers
//   (PV 128 MFMAs in 4 V-quartered passes + K prefetch). 1 barrier per step.
//   Dynamic LDS 128KB: K dbuf 2x32KB (256 rows x 128B, data in lo 64B,
//   swizzle ^((j&7)<<4) -> <=2-way banks), P dbuf 2x32KB (64 rows x 512B,
//   swizzle ^(m<<4), <=2-way on b64 write / b128 read).
// ---------------------------------------------------------------------------

#define QTR(QI, VCUR, VNXT) do {                                               \
    if ((QI) < 3) {                                                            \
        _Pragma("unroll")                                                      \
        for (int cf = 0; cf < 4; ++cf) {                                       \
            VNXT[cf * 2]     = *(const uint4*)&vrow[cf][_jb + ((QI) + 1) * 64 + g * 8];      \
            VNXT[cf * 2 + 1] = *(const uint4*)&vrow[cf][_jb + ((QI) + 1) * 64 + 32 + g * 8]; \
        }                                                                      \
    }                                                                          \
    short8 pf[4][2];                                                           \
    _Pragma("unroll")                                                          \
    for (int f = 0; f < 4; ++f)                                                \
        _Pragma("unroll")                                                      \
        for (int kk = 0; kk < 2; ++kk)                                         \
            pf[f][kk] = __builtin_bit_cast(short8, *(const uint4*)(pb +        \
                (f * 16 + m) * 512 + (((((QI) * 2 + kk) * 64) + g * 16) ^ (m << 4)))); \
    __builtin_amdgcn_s_setprio(1);                                             \
    _Pragma("unroll")                                                          \
    for (int cf = 0; cf < 4; ++cf) {                                           \
        short8 v0s = __builtin_bit_cast(short8, VCUR[cf * 2]);                 \
        short8 v1s = __builtin_bit_cast(short8, VCUR[cf * 2 + 1]);             \
        _Pragma("unroll")                                                      \
        for (int f = 0; f < 4; ++f) {                                          \
            acc[cf][f] = __builtin_amdgcn_mfma_f32_16x16x32_bf16(v0s, pf[f][0], acc[cf][f], 0, 0, 0); \
            acc[cf][f] = __builtin_amdgcn_mfma_f32_16x16x32_bf16(v1s, pf[f][1], acc[cf][f], 0, 0, 0); \
        }                                                                      \
    }                                                                          \
    __builtin_amdgcn_s_setprio(0);                                             \
} while (0)

#define CONSPV(JT) do {                                                        \
    const char* pb = Pbase + ((((JT) & 1) ^ 1) * 32768);                       \
    const int _jb = ((JT) - 1) * 256;                                          \
    float ff[4];                                                               \
    _Pragma("unroll")                                                          \
    for (int f = 0; f < 4; ++f) ff[f] = sFac[((JT) & 1) ^ 1][f * 16 + m];      \
    if (!__all(ff[0] == 1.f && ff[1] == 1.f && ff[2] == 1.f && ff[3] == 1.f)) { \
        _Pragma("unroll")                                                      \
        for (int cf = 0; cf < 4; ++cf)                                         \
            _Pragma("unroll")                                                  \
            for (int f = 0; f < 4; ++f) acc[cf][f] *= ff[f];                   \
    }                                                                          \
    uint4 va[8], vb2[8];                                                       \
    _Pragma("unroll")                                                          \
    for (int cf = 0; cf < 4; ++cf) {                                           \
        va[cf * 2]     = *(const uint4*)&vrow[cf][_jb + g * 8];                \
        va[cf * 2 + 1] = *(const uint4*)&vrow[cf][_jb + 32 + g * 8];           \
    }                                                                          \
    QTR(0, va, vb2); QTR(1, vb2, va); QTR(2, va, vb2); QTR(3, vb2, va);        \
} while (0)

__global__ __launch_bounds__(512, 2) void attn_kernel(
    const unsigned short* __restrict__ Qh, const unsigned short* __restrict__ Ql,
    const unsigned short* __restrict__ Kh, const unsigned short* __restrict__ Vb,
    const float* __restrict__ x, const float* __restrict__ gamma,
    float* __restrict__ out)
{
    extern __shared__ char smem[];          // [0,64K): K dbuf  [64K,128K): P dbuf
    __shared__ float sFac[2][64];
    __shared__ float sL[64];

    char* const Kbase = smem;
    char* const Pbase = smem + 65536;

    // XCD swizzle: 2 XCDs per batch
    const int bid = blockIdx.x;
    const int b   = (bid & 7) >> 1;
    const int it  = (bid >> 3) + ((bid & 1) << 5);
    const int i0  = it * 64;

    const int t   = threadIdx.x;
    const int wv8 = t >> 6;
    const bool isProd = (wv8 < 4);
    const int w   = wv8 & 3;
    const int l   = t & 63, g = l >> 4, m = l & 15;
    const int irow = w * 16 + m;

    // ---- prologue: stage K tile 0 (rows t>>2 and +128), swizzled 128B rows
    {
        const int sj = t >> 2, sq = t & 3;
        const int kwr = sj * 128 + ((sq * 16) ^ ((sj & 7) << 4));
        const size_t gb = ((size_t)b * NPIX + sj) * CQK + sq * 8;
        *(uint4*)&Kbase[kwr]         = *(const uint4*)&Kh[gb];
        *(uint4*)&Kbase[kwr + 16384] = *(const uint4*)&Kh[gb + (size_t)128 * CQK];
    }

    // ---- producer state ----
    short8 qh = {}, ql = {};
    float m_run = -1e30f, l_run = 0.f;
    if (isProd) {
        const int iq = i0 + irow;
        qh = __builtin_bit_cast(short8, *(const uint4*)&Qh[((size_t)b * NPIX + iq) * CQK + g * 8]);
        ql = __builtin_bit_cast(short8, *(const uint4*)&Ql[((size_t)b * NPIX + iq) * CQK + g * 8]);
    }

    // ---- consumer state ----
    f32x4 acc[4][4];
    #pragma unroll
    for (int cf = 0; cf < 4; ++cf)
        #pragma unroll
        for (int f = 0; f < 4; ++f) acc[cf][f] = (f32x4){0.f, 0.f, 0.f, 0.f};
    const unsigned short* vrow[4];
    size_t kpf_base = 0;
    int kwr0 = 0;
    if (!isProd) {
        #pragma unroll
        for (int cf = 0; cf < 4; ++cf)
            vrow[cf] = Vb + ((size_t)b * CH + w * 64 + cf * 16 + m) * NPIX;
        const int t2  = t & 255;
        const int sj0 = t2 >> 2, sq0 = t2 & 3;    // rows 0..63 (+64k), dword quads
        kpf_base = ((size_t)b * NPIX + sj0) * CQK + sq0 * 8;
        kwr0 = sj0 * 128 + ((sq0 * 16) ^ ((sj0 & 7) << 4));
    }

    __syncthreads();

    for (int jt = 0; jt < NT; ++jt) {
        const int idx = jt & 1;

        if (isProd) {
            // ---- QK^T: 16 j-tiles x 2 compensated MFMAs ----
            const char* kb = Kbase + idx * 32768;
            f32x4 sv[16];
            #pragma unroll
            for (int jf = 0; jf < 16; ++jf) {
                short8 kh8 = __builtin_bit_cast(short8, *(const uint4*)&kb[
                    jf * 2048 + m * 128 + ((g * 16) ^ ((m & 7) << 4))]);
                f32x4 s = (f32x4){0.f, 0.f, 0.f, 0.f};
                s = __builtin_amdgcn_mfma_f32_16x16x32_bf16(kh8, qh, s, 0, 0, 0);
                s = __builtin_amdgcn_mfma_f32_16x16x32_bf16(kh8, ql, s, 0, 0, 0);
                sv[jf] = s;
            }
            float sc[64];
            #pragma unroll
            for (int jf = 0; jf < 16; ++jf)
                #pragma unroll
                for (int r = 0; r < 4; ++r) sc[jf * 4 + r] = sv[jf][r];

            // ---- in-lane tree max over 64 ----
            float mx[32];
            #pragma unroll
            for (int k = 0; k < 32; ++k) mx[k] = fmaxf(sc[k], sc[k + 32]);
            #pragma unroll
            for (int k = 0; k < 16; ++k) mx[k] = fmaxf(mx[k], mx[k + 16]);
            #pragma unroll
            for (int k = 0; k < 8; ++k) mx[k] = fmaxf(mx[k], mx[k + 8]);
            #pragma unroll
            for (int k = 0; k < 4; ++k) mx[k] = fmaxf(mx[k], mx[k + 4]);
            float tmax = fmaxf(fmaxf(mx[0], mx[2]), fmaxf(mx[1], mx[3]));

            // ---- gated defer-max ----
            float fac = 1.0f;
            if (!__all(tmax <= m_run + 11.5f)) {
                float tc = fmaxf(tmax, __shfl_xor(tmax, 16));
                tc = fmaxf(tc, __shfl_xor(tc, 32));
                float mt = fmaxf(m_run, tc);
                fac = exp2_fast(m_run - mt);
                m_run = mt;
            }

            #pragma unroll
            for (int k = 0; k < 64; ++k) sc[k] = exp2_fast(sc[k] - m_run);
            float sm[32];
            #pragma unroll
            for (int k = 0; k < 32; ++k) sm[k] = sc[k] + sc[k + 32];
            #pragma unroll
            for (int k = 0; k < 16; ++k) sm[k] = sm[k] + sm[k + 16];
            #pragma unroll
            for (int k = 0; k < 8; ++k) sm[k] = sm[k] + sm[k + 8];
            #pragma unroll
            for (int k = 0; k < 4; ++k) sm[k] = sm[k] + sm[k + 4];
            float tsum = (sm[0] + sm[2]) + (sm[1] + sm[3]);
            tsum += __shfl_xor(tsum, 16);
            tsum += __shfl_xor(tsum, 32);
            l_run = l_run * fac + tsum;
            if (g == 0) sFac[idx][irow] = fac;

            // ---- pack P -> bf16, swizzled ----
            char* pbw = Pbase + idx * 32768;
            #pragma unroll
            for (int jf = 0; jf < 16; ++jf) {
                uint2 u;
                u.x = cvt_pk_bf16(sc[jf * 4 + 0], sc[jf * 4 + 1]);
                u.y = cvt_pk_bf16(sc[jf * 4 + 2], sc[jf * 4 + 3]);
                *(uint2*)(pbw + irow * 512 + ((jf * 32 + g * 8) ^ (m << 4))) = u;
            }
        } else {
            const bool doK = (jt < NT - 1);
            uint4 pk[4];
            if (doK) {
                #pragma unroll
                for (int r = 0; r < 4; ++r)
                    pk[r] = *(const uint4*)&Kh[kpf_base +
                        (size_t)((jt + 1) * 256 + r * 64) * CQK];
            }
            if (jt >= 1) CONSPV(jt);
            if (doK) {
                char* kb = Kbase + (idx ^ 1) * 32768;
                #pragma unroll
                for (int r = 0; r < 4; ++r)
                    *(uint4*)&kb[kwr0 + r * 8192] = pk[r];
            }
        }

        __syncthreads();
    }

    // ---- tail: publish denominators, final PV, epilogue ----
    if (isProd) {
        if (g == 0) sL[irow] = l_run;
    }
    __syncthreads();
    if (!isProd) {
        CONSPV(NT);
        const float gm = gamma[0];
        #pragma unroll
        for (int f = 0; f < 4; ++f) {
            float linv = 1.0f / sL[f * 16 + m];
            #pragma unroll
            for (int cf = 0; cf < 4; ++cf) {
                #pragma unroll
                for (int r = 0; r < 4; ++r) {
                    int c = w * 64 + cf * 16 + g * 4 + r;
                    size_t o = ((size_t)b * CH + c) * NPIX + i0 + f * 16 + m;
                    out[o] = gm * acc[cf][f][r] * linv + x[o];
                }
            }
        }
    }
}

extern "C" void kernel_launch(void* const* d_in, const int* in_sizes, int n_in,
                              void* d_out, int out_size, void* d_ws, size_t ws_size,
                              hipStream_t stream) {
    const float* x     = (const float*)d_in[0];
    const float* wq    = (const float*)d_in[1];
    const float* bq    = (const float*)d_in[2];
    const float* wk    = (const float*)d_in[3];
    const float* bk    = (const float*)d_in[4];
    const float* wv    = (const float*)d_in[5];
    const float* bv    = (const float*)d_in[6];
    const float* gamma = (const float*)d_in[7];
    float* out = (float*)d_out;

    // ws layout (bf16): Qh|Ql|Kh (1MB each) | Vb (8MB) | Wh|Wl (160KB each)
    unsigned short* base = (unsigned short*)d_ws;
    const size_t qk_sz = (size_t)BATCH * NPIX * CQK;   // 524288
    unsigned short* Qh = base;
    unsigned short* Ql = Qh + qk_sz;
    unsigned short* Kh = Ql + qk_sz;
    unsigned short* Vb = Kh + qk_sz;
    unsigned short* Wh = Vb + (size_t)BATCH * CH * NPIX;
    unsigned short* Wl = Wh + 320 * 256;

    wcvt_kernel<<<320, 256, 0, stream>>>(wq, wk, wv, Wh, Wl);
    qkv_kernel<<<dim3(128, 4), 256, 0, stream>>>(x, bq, bk, bv, Wh, Wl,
                                                 Qh, Ql, Kh, Vb);
    attn_kernel<<<256, 512, 131072, stream>>>(Qh, Ql, Kh, Vb, x, gamma, out);
}